// Round 22
// baseline (29.312 us; speedup 1.0000x reference)
//
#include <hip/hip_runtime.h>
#include <stdint.h>

// MosaicSDF: N=1024 points, G=512 grids, K=7 (343 nodes/grid).
// R22: grid-major, single compute kernel + small memset node.
// Root cause of the 14-16.5us plateau (R12-R21): every active pair
// re-fetches its 1.4KB row from L2 (~1.5M L1 line-fills, invariant
// under all lane layouts). Grid-major stages each row in LDS ONCE and
// reuses it for all its active pairs (fills drop ~65x).
//   Writers (bid<1024): block = (grid g, 512-point half). Stage row;
//     sweep 512 points (2 ballot rounds/wave): actives -> LDS compaction
//     + atomicAdd(den[n], gwr). Drain: 32 8-lane groups, R12's slab
//     math from the shared row (broadcast LDS reads); sub==0 does
//     atomicAdd(num[pid], interp*gw). Final __syncthreads (compiler
//     drains vmcnt -> atomics complete) then t0: atomicAdd(done,1).
//     NO threadfence anywhere (R15's killer) - atomics are device-
//     coherent on their own.
//   Reducers (bid>=1024): 4 blocks x 256 pts. One lane polls done==1024
//     with s_sleep backoff (no CAS storm), barrier, then atomic-read
//     num/den and write out. All 1028 blocks co-resident (<=8/CU) ->
//     spin-safe; writers never wait on reducers.
//   Zero-init of num/den/done via hipMemsetAsync node (12KB, replayed
//   in-graph every iteration -> correct from any prior state).

#define NPTS   1024
#define NGRIDS 512
#define NWRT   1024            // 2 writer blocks per grid
#define NRED   4
#define STEP   (1.0f / 6.0f)
#define FSQRT(x) __builtin_amdgcn_sqrtf(x)

__global__ __launch_bounds__(256) void msdf_gm(
    const float* __restrict__ points,    // (N,3)
    const float* __restrict__ centers,   // (G,3)
    const float* __restrict__ scales,    // (G,)
    const float* __restrict__ vals,      // (G,343)
    float* __restrict__ out,             // (N,)
    float* __restrict__ num,             // ws (pre-zeroed)
    float* __restrict__ den,             // ws (pre-zeroed)
    unsigned int* done)                  // ws (pre-zeroed)
{
    __shared__ float  s_row[344];
    __shared__ float4 s_pr[4][128];      // (rx,ry,rz,gwr) per active
    __shared__ unsigned short s_pid[4][128];
    __shared__ int    s_c[4];

    const int bid  = blockIdx.x;
    const int t    = threadIdx.x;
    const int w    = t >> 6;
    const int lane = t & 63;

    if (bid < NWRT) {
        // ================= writer: (grid, half) =================
        const int g  = bid >> 1;
        const int nb = (bid & 1) << 9;

        // Stage this grid's row once (reused by all its active pairs).
        s_row[t] = vals[g * 343 + t];
        if (t < 87) s_row[t + 256] = vals[g * 343 + t + 256];

        const float cx   = centers[g * 3 + 0];       // block-uniform
        const float cy   = centers[g * 3 + 1];
        const float cz   = centers[g * 3 + 2];
        const float invs = 1.0f / scales[g];

        // ---- Phase A: sweep 512 points; compact actives; den atomics ----
        int cbase = 0;
        #pragma unroll
        for (int r = 0; r < 2; ++r) {
            const int pl = (r << 8) + (w << 6) + lane;   // 0..511
            const int n  = nb + pl;
            const float rx = (points[n * 3 + 0] - cx) * invs;
            const float ry = (points[n * 3 + 1] - cy) * invs;
            const float rz = (points[n * 3 + 2] - cz) * invs;
            const float gwr = 1.0f - FSQRT(rx * rx + ry * ry + rz * rz);
            const bool  act = (gwr > 0.0f);
            const unsigned long long m = __ballot(act);
            if (act) {
                const int pos = cbase + (int)__popcll(m & ((1ull << lane) - 1ull));
                s_pr[w][pos]  = make_float4(rx, ry, rz, gwr);
                s_pid[w][pos] = (unsigned short)n;
                atomicAdd(&den[n], gwr);
            }
            cbase += (int)__popcll(m);
        }
        if (lane == 0) s_c[w] = cbase;
        __syncthreads();

        const int o1 = s_c[0];
        const int o2 = o1 + s_c[1];
        const int o3 = o2 + s_c[2];
        const int C  = o3 + s_c[3];

        // ---- Phase B: 32 8-lane groups drain actives from shared row ----
        const int grp = t >> 3;
        const int sub = t & 7;

        for (int a = grp; a < C; a += 32) {
            const int seg = (a >= o1) + (a >= o2) + (a >= o3);
            const int b0  = (seg == 0) ? 0 : (seg == 1) ? o1
                          : (seg == 2) ? o2 : o3;
            const float4 pr  = s_pr[seg][a - b0];
            const int    pid = (int)s_pid[seg][a - b0];

            float dy2[7], dz2[7];                    // static-indexed -> regs
            #pragma unroll
            for (int j = 0; j < 7; ++j) { const float d = pr.y - j * STEP; dy2[j] = d * d; }
            #pragma unroll
            for (int l = 0; l < 7; ++l) { const float d = pr.z - l * STEP; dz2[l] = d * d; }

            const int   slab = (sub < 7) ? sub : 6;
            const float dxv  = pr.x - slab * STEP;
            const float dx2  = (sub < 7) ? dxv * dxv : 4.0f;   // sub==7 -> wt 0
            const float* __restrict__ vrow = s_row + slab * 49;

            float ws = 0.0f, vs = 0.0f;
            #pragma unroll
            for (int j = 0; j < 7; ++j) {
                const float dxy = dx2 + dy2[j];
                #pragma unroll
                for (int l = 0; l < 7; ++l) {
                    const float d2 = dxy + dz2[l];
                    const float wt = (d2 <= 1.0f) ? FSQRT(d2) : 0.0f;
                    ws += wt;
                    vs  = fmaf(wt, vrow[j * 7 + l], vs);   // broadcast LDS
                }
            }
            #pragma unroll
            for (int o = 4; o >= 1; o >>= 1) {
                ws += __shfl_xor(ws, o);
                vs += __shfl_xor(vs, o);
            }
            if (sub == 0) {
                const float interp = (ws > 0.0f) ? (vs / ws) : 0.0f;
                atomicAdd(&num[pid], interp * pr.w);
            }
        }

        // Barrier drains vmcnt (compiler) -> block's atomics complete.
        __syncthreads();
        if (t == 0) atomicAdd(done, 1u);
    } else {
        // ================= reducer: 256 points =================
        const int n = ((bid - NWRT) << 8) + t;
        if (t == 0) {
            while (atomicCAS(done, 0u, 0u) < (unsigned)NWRT)
                __builtin_amdgcn_s_sleep(2);
        }
        __syncthreads();
        const float dn = atomicAdd(&den[n], 0.0f);   // coherent atomic read
        const float nm = atomicAdd(&num[n], 0.0f);
        out[n] = (dn > 0.0f) ? (nm / dn) : 0.0f;
    }
}

extern "C" void kernel_launch(void* const* d_in, const int* in_sizes, int n_in,
                              void* d_out, int out_size, void* d_ws, size_t ws_size,
                              hipStream_t stream) {
    const float* points  = (const float*)d_in[0];   // (1024,3)
    const float* centers = (const float*)d_in[1];   // (512,3)
    const float* scales  = (const float*)d_in[2];   // (512,)
    const float* vals    = (const float*)d_in[3];   // (512,7,7,7)
    float* out = (float*)d_out;                     // (1024,)

    float*        num  = (float*)d_ws;                          // @0
    float*        den  = num + 1024;                            // @4096
    unsigned int* done = (unsigned int*)((char*)d_ws + 8192);   // @8192

    hipMemsetAsync(d_ws, 0, 12288, stream);
    msdf_gm<<<NWRT + NRED, 256, 0, stream>>>(points, centers, scales, vals,
                                             out, num, den, done);
}

// Round 23
// 14.261 us; speedup vs baseline: 2.0554x; 2.0554x over previous
//
#include <hip/hip_runtime.h>

// MosaicSDF: N=1024 points, G=512 grids, K=7 (343 nodes/grid).
// FINAL (= R18, best measured: 14.12us, absmax 0). Session summary:
// point-major, single dispatch, no staging, max occupancy.
//   - R12-R21 showed phase 2 is a multi-way equilibrium (load issue /
//     sqrt chains / reduce shuffles / active-count tail); the only real
//     win was dropping LDS row staging + running 4 blocks/CU (R18).
//   - Refuted alternatives: vector staging (scratch spill), grid-major
//     (extra dispatch or atomic/fence coordination), cooperative launch
//     (graph-capture incompatible), wide/coalesced load reshapes (null
//     to negative).
//   Phase 1: wave w sweeps 128 grids for point w>>2 (2 ballot rounds);
//     ballot-scan compacts (rx,ry,rz,gwr)+gid per wave segment.
//   Phase 2: 32 16-lane groups drain pooled actives (CT=C0+C1); lane
//     owns (i,j)-rows {sub,sub+16,sub+32} (7 nodes each, mul-shift
//     div-7 decode) + row-48 tail, read direct from L2 (vals=700KB,
//     L2-resident); static dz2 table; 4-step group reduce.
//   No atomics, no workspace, one dispatch, ~18.4KB LDS -> 4 blocks/CU.

#define NPTS   1024
#define NGRIDS 512
#define TPB    512
#define NBLK   512             // 2 points per block
#define STEP   (1.0f / 6.0f)
#define FSQRT(x) __builtin_amdgcn_sqrtf(x)

__global__ __launch_bounds__(TPB, 4) void msdf_fused(
    const float* __restrict__ points,    // (N,3)
    const float* __restrict__ centers,   // (G,3)
    const float* __restrict__ scales,    // (G,)
    const float* __restrict__ vals,      // (G,343)
    float* __restrict__ out)             // (N,)
{
    __shared__ float4 s_pair[8][128];         // 16,384 B (rx,ry,rz,gwr)
    __shared__ unsigned short s_gid[8][128];  // 2,048 B
    __shared__ int   s_c[8];
    __shared__ float s_d[8];
    __shared__ float s_red[8][2];

    const int bid  = blockIdx.x;
    const int t    = threadIdx.x;
    const int w    = t >> 6;             // wave 0..7
    const int lane = t & 63;
    const int grp  = t >> 4;             // 0..31: 16-lane group (pair slot)
    const int sub  = t & 15;

    const int   n  = (bid << 1) + (w >> 2);  // this wave's point
    const float px = points[n * 3 + 0];      // wave-uniform -> scalar loads
    const float py = points[n * 3 + 1];
    const float pz = points[n * 3 + 2];

    // ---- Phase 1: activity sweep + ballot-scan compaction ----
    float dsum  = 0.0f;
    int   cbase = 0;
    #pragma unroll
    for (int r = 0; r < 2; ++r) {
        const int g = ((w & 3) << 7) + (r << 6) + lane;  // wave's 128 grids
        const float invs = 1.0f / scales[g];
        const float rx = (px - centers[g * 3 + 0]) * invs;
        const float ry = (py - centers[g * 3 + 1]) * invs;
        const float rz = (pz - centers[g * 3 + 2]) * invs;
        const float gwr = 1.0f - FSQRT(rx * rx + ry * ry + rz * rz);
        const bool  act = (gwr > 0.0f);
        const unsigned long long m = __ballot(act);
        if (act) {
            const int pos = cbase + (int)__popcll(m & ((1ull << lane) - 1ull));
            s_pair[w][pos] = make_float4(rx, ry, rz, gwr);
            s_gid[w][pos]  = (unsigned short)g;
            dsum += gwr;
        }
        cbase += (int)__popcll(m);
    }
    #pragma unroll
    for (int o = 32; o >= 1; o >>= 1) dsum += __shfl_xor(dsum, o);
    if (lane == 0) { s_c[w] = cbase; s_d[w] = dsum; }
    __syncthreads();

    const int o1 = s_c[0];
    const int o2 = o1 + s_c[1];
    const int o3 = o2 + s_c[2];
    const int o4 = o3 + s_c[3];
    const int o5 = o4 + s_c[4];
    const int o6 = o5 + s_c[5];
    const int o7 = o6 + s_c[6];
    const int CT = o7 + s_c[7];
    const float den0 = s_d[0] + s_d[1] + s_d[2] + s_d[3];
    const float den1 = s_d[4] + s_d[5] + s_d[6] + s_d[7];

    // ---- Phase 2: 32 16-lane groups, direct-from-L2 rows ----
    float acc0 = 0.0f, acc1 = 0.0f;
    for (int a = grp; a < CT; a += 32) {
        const int seg = (a >= o1) + (a >= o2) + (a >= o3) + (a >= o4)
                      + (a >= o5) + (a >= o6) + (a >= o7);
        const int b0  = (seg == 0) ? 0 : (seg == 1) ? o1
                      : (seg == 2) ? o2 : (seg == 3) ? o3
                      : (seg == 4) ? o4 : (seg == 5) ? o5
                      : (seg == 6) ? o6 : o7;
        const float4 pr  = s_pair[seg][a - b0];
        const int    gid = (int)s_gid[seg][a - b0];
        const float* __restrict__ grow = vals + gid * 343;

        float dz2[7];                                // static-indexed -> regs
        #pragma unroll
        for (int l = 0; l < 7; ++l) { const float d = pr.z - l * STEP; dz2[l] = d * d; }

        float ws = 0.0f, vs = 0.0f;
        #pragma unroll
        for (int rr = 0; rr < 3; ++rr) {
            const int rowid = sub + (rr << 4);       // 0..47
            const int i = (rowid * 9363) >> 16;      // rowid / 7
            const int j = rowid - i * 7;
            const float dxv = pr.x - (float)i * STEP;
            const float dyv = pr.y - (float)j * STEP;
            const float dxy = dxv * dxv + dyv * dyv;
            const float* __restrict__ vr = grow + rowid * 7;   // L1/L2-hit
            #pragma unroll
            for (int l = 0; l < 7; ++l) {
                const float d2 = dxy + dz2[l];
                const float wt = (d2 <= 1.0f) ? FSQRT(d2) : 0.0f;
                ws += wt;
                vs  = fmaf(wt, vr[l], vs);
            }
        }
        if (sub < 7) {                               // row 48: node (6,6,sub)
            const float dxv = pr.x - 1.0f;
            const float dyv = pr.y - 1.0f;
            const float dzv = pr.z - (float)sub * STEP;
            const float d2  = dxv * dxv + dyv * dyv + dzv * dzv;
            const float wt  = (d2 <= 1.0f) ? FSQRT(d2) : 0.0f;
            ws += wt;
            vs  = fmaf(wt, grow[336 + sub], vs);
        }
        #pragma unroll
        for (int o = 8; o >= 1; o >>= 1) {
            ws += __shfl_xor(ws, o);
            vs += __shfl_xor(vs, o);
        }
        const float interp = (ws > 0.0f) ? (vs / ws) : 0.0f;
        if (sub == 0) {
            const float contrib = interp * pr.w;
            if (seg < 4) acc0 += contrib;
            else         acc1 += contrib;
        }
    }

    // Block reduction: butterfly per wave, then cross-wave via LDS.
    #pragma unroll
    for (int o = 32; o >= 1; o >>= 1) {
        acc0 += __shfl_xor(acc0, o);
        acc1 += __shfl_xor(acc1, o);
    }
    if (lane == 0) { s_red[w][0] = acc0; s_red[w][1] = acc1; }
    __syncthreads();
    if (t < 2) {
        float nm = 0.0f;
        #pragma unroll
        for (int i = 0; i < 8; ++i) nm += s_red[i][t];
        const float dn = (t == 0) ? den0 : den1;
        out[(bid << 1) + t] = (dn > 0.0f) ? (nm / dn) : 0.0f;
    }
}

extern "C" void kernel_launch(void* const* d_in, const int* in_sizes, int n_in,
                              void* d_out, int out_size, void* d_ws, size_t ws_size,
                              hipStream_t stream) {
    const float* points  = (const float*)d_in[0];   // (1024,3)
    const float* centers = (const float*)d_in[1];   // (512,3)
    const float* scales  = (const float*)d_in[2];   // (512,)
    const float* vals    = (const float*)d_in[3];   // (512,7,7,7)
    float* out = (float*)d_out;                     // (1024,)

    msdf_fused<<<NBLK, TPB, 0, stream>>>(points, centers, scales, vals, out);
}